// Round 1
// baseline (1955.221 us; speedup 1.0000x reference)
//
#include <hip/hip_runtime.h>

#define NN 16384
#define NE 524288
#define HID 36
#define NCLS 16
#define SPLITK 8
#define KSLICE (NN / SPLITK)

// ---------- CSR build ----------
__global__ void k_zero_int(int* __restrict__ p, int n) {
  int i = blockIdx.x * blockDim.x + threadIdx.x;
  if (i < n) p[i] = 0;
}

__global__ void k_count(const int* __restrict__ dst, int* __restrict__ cnt) {
  int i = blockIdx.x * blockDim.x + threadIdx.x;
  if (i < NE) atomicAdd(&cnt[dst[i]], 1);
}

// single block, 256 threads: exclusive prefix sum over 16384 counts,
// also writes dis[i] = rsqrt(deg_i + 1)  (self-loop included => deg>=1 always)
__global__ void k_scan(const int* __restrict__ cnt, int* __restrict__ off,
                       int* __restrict__ cur, float* __restrict__ dis) {
  __shared__ int part[256];
  const int t = threadIdx.x;
  const int base = t * 64;
  int s = 0;
  for (int i = 0; i < 64; ++i) s += cnt[base + i];
  part[t] = s;
  __syncthreads();
  if (t == 0) {
    int run = 0;
    for (int i = 0; i < 256; ++i) { int v = part[i]; part[i] = run; run += v; }
    off[NN] = run;
  }
  __syncthreads();
  int run = part[t];
  for (int i = 0; i < 64; ++i) {
    int idx = base + i;
    off[idx] = run;
    cur[idx] = run;
    run += cnt[idx];
    dis[idx] = rsqrtf((float)(cnt[idx] + 1));
  }
}

__global__ void k_scatter(const int* __restrict__ src, const int* __restrict__ dst,
                          int* __restrict__ cur, int* __restrict__ esrc) {
  int i = blockIdx.x * blockDim.x + threadIdx.x;
  if (i < NE) {
    int p = atomicAdd(&cur[dst[i]], 1);
    esrc[p] = src[i];
  }
}

// ---------- big GEMM: x[N,N] @ W1[N,36] with split-K, partials ----------
__global__ void __launch_bounds__(256) k_gemm1(const float* __restrict__ x,
                                               const float* __restrict__ W,
                                               float* __restrict__ part) {
  const int rb = blockIdx.x & 63;   // 64 row-blocks of 256 rows
  const int s  = blockIdx.x >> 6;   // split-k slice (8)
  const int r  = rb * 256 + threadIdx.x;
  const int k0 = s * KSLICE;
  const float* __restrict__ a  = x + (size_t)r * NN + k0;
  const float* __restrict__ wp = W + (size_t)k0 * HID;
  float acc[HID];
#pragma unroll
  for (int c = 0; c < HID; ++c) acc[c] = 0.0f;
  for (int kk = 0; kk < KSLICE; kk += 16) {
    const float4 a0 = *(const float4*)(a + kk + 0);
    const float4 a1 = *(const float4*)(a + kk + 4);
    const float4 a2 = *(const float4*)(a + kk + 8);
    const float4 a3 = *(const float4*)(a + kk + 12);
    float av[16] = {a0.x, a0.y, a0.z, a0.w, a1.x, a1.y, a1.z, a1.w,
                    a2.x, a2.y, a2.z, a2.w, a3.x, a3.y, a3.z, a3.w};
    const float* __restrict__ wrow = wp + (size_t)kk * HID;
#pragma unroll
    for (int j = 0; j < 16; ++j) {
      const float aj = av[j];
#pragma unroll
      for (int c = 0; c < HID; ++c)
        acc[c] = fmaf(aj, wrow[j * HID + c], acc[c]);
    }
  }
  float* __restrict__ po = part + (size_t)s * NN * HID + (size_t)r * HID;
#pragma unroll
  for (int c4 = 0; c4 < HID / 4; ++c4)
    ((float4*)po)[c4] = make_float4(acc[4 * c4 + 0], acc[4 * c4 + 1],
                                    acc[4 * c4 + 2], acc[4 * c4 + 3]);
}

__global__ void k_reduce(const float* __restrict__ part, float* __restrict__ o, int n) {
  int i = blockIdx.x * blockDim.x + threadIdx.x;
  if (i < n) {
    float s = 0.0f;
#pragma unroll
    for (int p = 0; p < SPLITK; ++p) s += part[(size_t)p * n + i];
    o[i] = s;
  }
}

// ---------- aggregation: out[i,f] = dis_i * sum_e dis_src * h[src,f] + dis_i^2 * h[i,f] + b[f] ----------
template <int F, bool RELU>
__global__ void k_agg(const float* __restrict__ h, const int* __restrict__ off,
                      const int* __restrict__ esrc, const float* __restrict__ dis,
                      const float* __restrict__ b, float* __restrict__ out) {
  const int tid = blockIdx.x * blockDim.x + threadIdx.x;
  const int i = tid / F;
  const int f = tid - i * F;
  const int beg = off[i], end = off[i + 1];
  float acc = 0.0f;
  for (int j = beg; j < end; ++j) {
    const int s = esrc[j];
    acc = fmaf(dis[s], h[(size_t)s * F + f], acc);
  }
  const float di = dis[i];
  float v = fmaf(di, acc, di * di * h[(size_t)i * F + f]) + b[f];
  if (RELU) v = fmaxf(v, 0.0f);
  out[tid] = v;
}

// ---------- small dense layers ----------
template <int IN, int OUT>
__global__ void k_mm(const float* __restrict__ h, const float* __restrict__ W,
                     float* __restrict__ o) {
  const int tid = blockIdx.x * blockDim.x + threadIdx.x;
  const int i = tid / OUT;
  const int c = tid - i * OUT;
  float acc = 0.0f;
#pragma unroll
  for (int k = 0; k < IN; ++k)
    acc = fmaf(h[(size_t)i * IN + k], W[k * OUT + c], acc);
  o[tid] = acc;
}

__global__ void k_softmax(const float* __restrict__ a, float* __restrict__ out) {
  const int i = blockIdx.x * blockDim.x + threadIdx.x;
  const float* __restrict__ p = a + (size_t)i * NCLS;
  float v[NCLS];
  float m = -3.0e38f;
#pragma unroll
  for (int c = 0; c < NCLS; ++c) { v[c] = p[c]; m = fmaxf(m, v[c]); }
  float s = 0.0f;
#pragma unroll
  for (int c = 0; c < NCLS; ++c) { v[c] = expf(v[c] - m); s += v[c]; }
  const float inv = 1.0f / s;
  float* __restrict__ q = out + (size_t)i * NCLS;
#pragma unroll
  for (int c = 0; c < NCLS; ++c) q[c] = v[c] * inv;
}

extern "C" void kernel_launch(void* const* d_in, const int* in_sizes, int n_in,
                              void* d_out, int out_size, void* d_ws, size_t ws_size,
                              hipStream_t stream) {
  const float* x  = (const float*)d_in[0];
  const int*   ei = (const int*)d_in[1];
  const float* W1 = (const float*)d_in[2];
  const float* b1 = (const float*)d_in[3];
  const float* W2 = (const float*)d_in[4];
  const float* b2 = (const float*)d_in[5];
  const float* W3 = (const float*)d_in[6];
  const float* b3 = (const float*)d_in[7];
  float* out = (float*)d_out;
  const int* e_src = ei;        // edge_index[0] = message sources
  const int* e_dst = ei + NE;   // edge_index[1] = aggregation targets

  char* base = (char*)d_ws;
  size_t cur_off = 0;
  auto alloc = [&](size_t bytes) -> void* {
    void* p = base + cur_off;
    cur_off = (cur_off + bytes + 255) & ~(size_t)255;
    return p;
  };
  float* part = (float*)alloc((size_t)SPLITK * NN * HID * sizeof(float));
  float* h36  = (float*)alloc((size_t)NN * HID * sizeof(float));
  float* a36  = (float*)alloc((size_t)NN * HID * sizeof(float));
  float* h16  = (float*)alloc((size_t)NN * NCLS * sizeof(float));
  float* a16  = (float*)alloc((size_t)NN * NCLS * sizeof(float));
  int*   cnt  = (int*)alloc(NN * sizeof(int));
  int*   offs = (int*)alloc((NN + 1) * sizeof(int));
  int*   curp = (int*)alloc(NN * sizeof(int));
  int*   es   = (int*)alloc(NE * sizeof(int));
  float* dis  = (float*)alloc(NN * sizeof(float));

  // CSR build (counting sort of edges by dst)
  k_zero_int<<<NN / 256, 256, 0, stream>>>(cnt, NN);
  k_count<<<NE / 256, 256, 0, stream>>>(e_dst, cnt);
  k_scan<<<1, 256, 0, stream>>>(cnt, offs, curp, dis);
  k_scatter<<<NE / 256, 256, 0, stream>>>(e_src, e_dst, curp, es);

  // layer 1
  k_gemm1<<<SPLITK * (NN / 256), 256, 0, stream>>>(x, W1, part);
  k_reduce<<<NN * HID / 256, 256, 0, stream>>>(part, h36, NN * HID);
  k_agg<HID, true><<<NN * HID / 256, 256, 0, stream>>>(h36, offs, es, dis, b1, a36);

  // layer 2
  k_mm<HID, HID><<<NN * HID / 256, 256, 0, stream>>>(a36, W2, h36);
  k_agg<HID, true><<<NN * HID / 256, 256, 0, stream>>>(h36, offs, es, dis, b2, a36);

  // layer 3 + softmax
  k_mm<HID, NCLS><<<NN * NCLS / 256, 256, 0, stream>>>(a36, W3, h16);
  k_agg<NCLS, false><<<NN * NCLS / 256, 256, 0, stream>>>(h16, offs, es, dis, b3, a16);
  k_softmax<<<NN / 256, 256, 0, stream>>>(a16, out);
}